// Round 8
// baseline (28048.773 us; speedup 1.0000x reference)
//
#include <hip/hip_runtime.h>
#include <cstdint>
#include <cstddef>

#define SEQ 4096
#define HID 512
#define NTHETA 5
#define NWRK 8                  // worker blocks, all claimed onto ONE XCD
#define SENT_BITS 0x40000000u   // 2.0f — |tanh| < 1, so never a real h value

typedef unsigned long long u64;

__device__ __forceinline__ float tanh_fast(float x) {
  x = fminf(fmaxf(x, -20.0f), 20.0f);
  const float e = __expf(2.0f * x);
  return (e - 1.0f) / (e + 1.0f);
}

// L1-bypass, L2-served load: sees same-XCD plain stores at L2-hit latency.
__device__ __forceinline__ u64 load_sc0_u64(const u64* p) {
  u64 u;
  asm volatile("global_load_dwordx2 %0, %1, off sc0\n\ts_waitcnt vmcnt(0)"
               : "=v"(u) : "v"(p) : "memory");
  return u;
}

// Butterfly sum over the 16-lane j-group: xor1/xor2 on the VALU (DPP
// quad_perm — keeps them OFF the DS pipe), xor4/xor8 via ds_swizzle.
__device__ __forceinline__ float red16(float v) {
  int p;
  p = __builtin_amdgcn_update_dpp(0, __float_as_int(v), 0xB1, 0xF, 0xF, true); // lane^1
  v += __int_as_float(p);
  p = __builtin_amdgcn_update_dpp(0, __float_as_int(v), 0x4E, 0xF, 0xF, true); // lane^2
  v += __int_as_float(p);
  v += __int_as_float(__builtin_amdgcn_ds_swizzle(__float_as_int(v), 0x101F)); // ^4
  v += __int_as_float(__builtin_amdgcn_ds_swizzle(__float_as_int(v), 0x201F)); // ^8
  return v;
}

// f4-chunk swizzle: logical f4 chunk f -> LDS slot z (2-way max on b128 reads)
__device__ __forceinline__ int swz(int f) {
  return (f & ~7) | ((f ^ (f >> 3)) & 7);
}

// C[4096,512] = act(A[4096,K] @ W[512,K]^T + bias + noise_plane)
__global__ __launch_bounds__(256) void gemm_bias_noise(
    const float* __restrict__ A, const float* __restrict__ W,
    const float* __restrict__ bias, const float* __restrict__ noise,
    float* __restrict__ C, int K, int doTanh)
{
  const int N = HID;
  const int bm = blockIdx.y, bn = blockIdx.x;
  const int tid = threadIdx.x;
  const int tx = tid & 15, ty = tid >> 4;
  const int row0 = bm * 64, col0 = bn * 64;
  __shared__ float As[16][68];
  __shared__ float Ws[16][68];
  float acc[4][4] = {{0.f, 0.f, 0.f, 0.f}, {0.f, 0.f, 0.f, 0.f},
                     {0.f, 0.f, 0.f, 0.f}, {0.f, 0.f, 0.f, 0.f}};
  const int lrow = tid >> 2, lkq = tid & 3;
  for (int kt = 0; kt < K; kt += 16) {
    const float4 av = *(const float4*)&A[(size_t)(row0 + lrow) * K + kt + lkq * 4];
    const float4 wv = *(const float4*)&W[(size_t)(col0 + lrow) * K + kt + lkq * 4];
    __syncthreads();
    As[lkq * 4 + 0][lrow] = av.x; As[lkq * 4 + 1][lrow] = av.y;
    As[lkq * 4 + 2][lrow] = av.z; As[lkq * 4 + 3][lrow] = av.w;
    Ws[lkq * 4 + 0][lrow] = wv.x; Ws[lkq * 4 + 1][lrow] = wv.y;
    Ws[lkq * 4 + 2][lrow] = wv.z; Ws[lkq * 4 + 3][lrow] = wv.w;
    __syncthreads();
#pragma unroll
    for (int k = 0; k < 16; ++k) {
      const float4 a = *(const float4*)&As[k][ty * 4];
      const float4 bq = *(const float4*)&Ws[k][tx * 4];
      const float a4[4] = {a.x, a.y, a.z, a.w};
      const float b4[4] = {bq.x, bq.y, bq.z, bq.w};
#pragma unroll
      for (int i = 0; i < 4; ++i)
#pragma unroll
        for (int j = 0; j < 4; ++j)
          acc[i][j] = fmaf(a4[i], b4[j], acc[i][j]);
    }
  }
  const float4 bv = *(const float4*)&bias[col0 + tx * 4];
#pragma unroll
  for (int i = 0; i < 4; ++i) {
    const int row = row0 + ty * 4 + i;
    const float4 nv = *(const float4*)&noise[(size_t)row * N + col0 + tx * 4];
    float4 o;
    o.x = acc[i][0] + bv.x + nv.x;
    o.y = acc[i][1] + bv.y + nv.y;
    o.z = acc[i][2] + bv.z + nv.z;
    o.w = acc[i][3] + bv.w + nv.w;
    if (doTanh) {
      o.x = tanh_fast(o.x); o.y = tanh_fast(o.y);
      o.z = tanh_fast(o.z); o.w = tanh_fast(o.w);
    }
    *(float4*)&C[(size_t)row * N + col0 + tx * 4] = o;
  }
}

// Pre-fill the h-exchange buffer (= out plane 0) with the sentinel bits.
__global__ void fill_sentinel(uint4* __restrict__ p, int n4) {
  const int i = blockIdx.x * blockDim.x + threadIdx.x;
  if (i < n4) p[i] = make_uint4(SENT_BITS, SENT_BITS, SENT_BITS, SENT_BITS);
}

// Sequential scan h_t = tanh(drive_t + W_hh @ h_{t-1}), workers on ONE XCD.
// 256 blocks launched; each reads HW_REG_XCC_ID, claims a per-XCD slot;
// first XCD to fill NWRK slots wins via CAS; all other blocks exit.
// Exchange protocol (r5 inversion FIXED):
//   producer: workgroup-scope u64 store  -> write-through into shared L2
//             + agent-scope u64 store    -> L3 (backstop, identical value)
//   consumer: sc0-only u64 poll          -> reads the SAME L2 (fast path)
//             every 64th iter agent load -> L3 (safety net)
// Compute core = r7 (proven): thread (i=tid>>4, j=tid&15) owns 4 rows x 32
// cols in 128 VGPRs; swizzled LDS double-buffer; 1 barrier; 8 b128 reads,
// 128 FMA, DPP+swizzle reduce; j==0 publishes and seeds next LDS buffer.
__global__ __launch_bounds__(256) void recurrence(
    const float* __restrict__ Whh, const float* __restrict__ drive,
    const float* __restrict__ h0, unsigned* __restrict__ hexch,
    int* __restrict__ claim)   // claim[0..7]=per-XCD counters, claim[8]=chosen
{
  __shared__ int s_worker, s_slot;
  const int tid = threadIdx.x;

  if (tid == 0) {
    int xcd;
    asm volatile("s_getreg_b32 %0, hwreg(HW_REG_XCC_ID)" : "=s"(xcd));
    xcd &= 7;
    const int slot = atomicAdd(&claim[xcd], 1);          // device-scope
    if (slot == NWRK - 1) {
      int expected = 0;
      __hip_atomic_compare_exchange_strong(&claim[8], &expected, xcd + 1,
                                           __ATOMIC_RELAXED, __ATOMIC_RELAXED,
                                           __HIP_MEMORY_SCOPE_AGENT);
    }
    int ch;
    do {
      ch = __hip_atomic_load(&claim[8], __ATOMIC_RELAXED,
                             __HIP_MEMORY_SCOPE_AGENT);
    } while (ch == 0);
    s_worker = (ch == xcd + 1 && slot < NWRK) ? 1 : 0;
    s_slot = slot;
  }
  __syncthreads();
  if (!s_worker) return;

  const int slot = s_slot;
  const int base = slot * 64;
  const int i = tid >> 4;        // row-quad 0..15
  const int j = tid & 15;        // col-slice 0..15

  __shared__ float hbuf[2][HID];

  // W slice -> 128 f32 regs
  float4 wv0[8], wv1[8], wv2[8], wv3[8];
#pragma unroll
  for (int c = 0; c < 8; ++c) {
    const size_t rb = (size_t)(base + 4 * i) * HID + 32 * j + 4 * c;
    wv0[c] = *(const float4*)&Whh[rb];
    wv1[c] = *(const float4*)&Whh[rb + HID];
    wv2[c] = *(const float4*)&Whh[rb + 2 * HID];
    wv3[c] = *(const float4*)&Whh[rb + 3 * HID];
  }

  // poller mapping: floats 2*tid, 2*tid+1 -> swizzled LDS position
  const int fp = tid >> 1;
  const int woff = swz(fp) * 4 + (tid & 1) * 2;
  const bool own = (tid >= slot * 32) && (tid < slot * 32 + 32);

  // own-output slot (j==0 lanes): f4 chunk 16*slot + i
  const int zo = swz(16 * slot + i);

  for (int t = 0; t < SEQ; ++t) {
    const int buf = t & 1;

    float4 dv = make_float4(0.f, 0.f, 0.f, 0.f);
    if (j == 0)
      dv = *(const float4*)&drive[(size_t)t * HID + base + 4 * i];

    if (t == 0) {
      hbuf[0][woff]     = h0[2 * tid];
      hbuf[0][woff + 1] = h0[2 * tid + 1];
    } else if (!own) {
      const u64* src = (const u64*)&hexch[(size_t)(t - 1) * HID + 2 * tid];
      u64 u = load_sc0_u64(src);
      int it = 0;
      while ((unsigned)u == SENT_BITS || (unsigned)(u >> 32) == SENT_BITS) {
        if ((++it & 63) == 0)
          u = __hip_atomic_load(src, __ATOMIC_RELAXED,
                                __HIP_MEMORY_SCOPE_AGENT);   // L3 safety net
        else
          u = load_sc0_u64(src);                              // L2 fast path
      }
      float2 hv;
      hv.x = __uint_as_float((unsigned)u);
      hv.y = __uint_as_float((unsigned)(u >> 32));
      *(float2*)&hbuf[buf][woff] = hv;
    }
    __syncthreads();
    // anchor dv here: its load issued pre-poll, forced resident before FMA
    asm volatile("" :: "v"(dv.x), "v"(dv.y), "v"(dv.z), "v"(dv.w));

    float a0 = 0.f, a1 = 0.f, a2 = 0.f, a3 = 0.f;
#pragma unroll
    for (int c = 0; c < 8; ++c) {
      const float4 h4 = *(const float4*)&hbuf[buf][(8 * j + ((c ^ j) & 7)) * 4];
      a0 = fmaf(wv0[c].x, h4.x, a0); a0 = fmaf(wv0[c].y, h4.y, a0);
      a0 = fmaf(wv0[c].z, h4.z, a0); a0 = fmaf(wv0[c].w, h4.w, a0);
      a1 = fmaf(wv1[c].x, h4.x, a1); a1 = fmaf(wv1[c].y, h4.y, a1);
      a1 = fmaf(wv1[c].z, h4.z, a1); a1 = fmaf(wv1[c].w, h4.w, a1);
      a2 = fmaf(wv2[c].x, h4.x, a2); a2 = fmaf(wv2[c].y, h4.y, a2);
      a2 = fmaf(wv2[c].z, h4.z, a2); a2 = fmaf(wv2[c].w, h4.w, a2);
      a3 = fmaf(wv3[c].x, h4.x, a3); a3 = fmaf(wv3[c].y, h4.y, a3);
      a3 = fmaf(wv3[c].w, h4.w, a3); a3 = fmaf(wv3[c].z, h4.z, a3);
    }
    a0 = red16(a0); a1 = red16(a1); a2 = red16(a2); a3 = red16(a3);

    if (j == 0) {
      const float y0 = tanh_fast(a0 + dv.x);
      const float y1 = tanh_fast(a1 + dv.y);
      const float y2 = tanh_fast(a2 + dv.z);
      const float y3 = tanh_fast(a3 + dv.w);
      u64* d64 = (u64*)&hexch[(size_t)t * HID + base + 4 * i];
      const u64 p01 = (u64)__float_as_uint(y0) | ((u64)__float_as_uint(y1) << 32);
      const u64 p23 = (u64)__float_as_uint(y2) | ((u64)__float_as_uint(y3) << 32);
      // L2 fast path: plain (workgroup-scope) stores, write-through into the
      // XCD-shared L2 where same-XCD sc0 polls read them.
      __hip_atomic_store(d64 + 0, p01, __ATOMIC_RELAXED,
                         __HIP_MEMORY_SCOPE_WORKGROUP);
      __hip_atomic_store(d64 + 1, p23, __ATOMIC_RELAXED,
                         __HIP_MEMORY_SCOPE_WORKGROUP);
      // L3 backstop (identical values -> any ordering/eviction is benign).
      __hip_atomic_store(d64 + 0, p01, __ATOMIC_RELAXED,
                         __HIP_MEMORY_SCOPE_AGENT);
      __hip_atomic_store(d64 + 1, p23, __ATOMIC_RELAXED,
                         __HIP_MEMORY_SCOPE_AGENT);
      // own values never leave the CU: seed next LDS buffer directly.
      *(float4*)&hbuf[buf ^ 1][zo * 4] = make_float4(y0, y1, y2, y3);
    }
  }
}

__global__ void copy_final(const float* __restrict__ src, float* __restrict__ dst) {
  dst[threadIdx.x] = src[threadIdx.x];
}

extern "C" void kernel_launch(void* const* d_in, const int* in_sizes, int n_in,
                              void* d_out, int out_size, void* d_ws, size_t ws_size,
                              hipStream_t stream) {
  const float* input    = (const float*)d_in[0];
  const float* internal = (const float*)d_in[1];
  const float* state    = (const float*)d_in[2];
  const float* W_ih     = (const float*)d_in[3];
  const float* W_hh     = (const float*)d_in[4];
  const float* bias     = (const float*)d_in[5];
  float* out = (float*)d_out;

  const size_t plane = (size_t)SEQ * HID;
  // hexch IS out plane 0 (hs): prefilled with sentinel, every element
  // overwritten exactly once by the recurrence.
  unsigned* hexch = (unsigned*)out;
  float*    drive = out + 5 * plane;   // rewritten by theta-GEMM k=4 afterwards
  int*      claim = (int*)d_ws;        // claim[0..7] counters, claim[8] chosen

  hipMemsetAsync(d_ws, 0, 16 * sizeof(int), stream);
  fill_sentinel<<<(SEQ * HID / 4 + 255) / 256, 256, 0, stream>>>(
      (uint4*)hexch, SEQ * HID / 4);

  dim3 gg(HID / 64, SEQ / 64);
  // drive = x @ W_ih^T + b + internal[0]   (no tanh)
  gemm_bias_noise<<<gg, 256, 0, stream>>>(input, W_ih, bias, internal, drive,
                                          HID, 0);
  // hs (out plane 0): 256 blocks self-select one XCD, 8 workers run the scan
  recurrence<<<256, 256, 0, stream>>>(W_hh, drive, state, hexch, claim);
  // theta rollouts: plane k -> plane k+1
  for (int k = 0; k < NTHETA; ++k) {
    gemm_bias_noise<<<gg, 256, 0, stream>>>(out + (size_t)k * plane, W_hh, bias,
                                            internal + (size_t)(k + 1) * plane,
                                            out + (size_t)(k + 1) * plane,
                                            HID, 1);
  }
  // final_state = hs[4095]
  copy_final<<<1, HID, 0, stream>>>(out + (size_t)4095 * HID, out + 6 * plane);
}

// Round 9
// 6781.590 us; speedup vs baseline: 4.1360x; 4.1360x over previous
//
#include <hip/hip_runtime.h>
#include <cstdint>
#include <cstddef>

#define SEQ 4096
#define HID 512
#define NTHETA 5
#define NBLK 8
#define SENT_BITS 0x40000000u   // 2.0f — |tanh| < 1, so never a real h value

__device__ __forceinline__ float tanh_fast(float x) {
  x = fminf(fmaxf(x, -20.0f), 20.0f);
  const float e = __expf(2.0f * x);
  return (e - 1.0f) / (e + 1.0f);
}

// Butterfly sum over 16-lane groups: xor1, xor2, xor8 on the VALU (DPP
// quad_perm / row_ror:8), only xor4 on the DS pipe (ds_swizzle).
__device__ __forceinline__ float red16(float v) {
  int p;
  p = __builtin_amdgcn_update_dpp(0, __float_as_int(v), 0xB1, 0xF, 0xF, true);  // ^1
  v += __int_as_float(p);
  p = __builtin_amdgcn_update_dpp(0, __float_as_int(v), 0x4E, 0xF, 0xF, true);  // ^2
  v += __int_as_float(p);
  v += __int_as_float(__builtin_amdgcn_ds_swizzle(__float_as_int(v), 0x101F)); // ^4
  p = __builtin_amdgcn_update_dpp(0, __float_as_int(v), 0x128, 0xF, 0xF, true); // row_ror:8 = ^8
  v += __int_as_float(p);
  return v;
}

// f4-chunk swizzle: logical f4 chunk f -> LDS slot (r7-proven; <=2-way reads,
// conflict-free scalar poll writes: 64 consecutive floats map onto 2 full
// 32-bank rows).
__device__ __forceinline__ int swz(int f) {
  return (f & ~7) | ((f ^ (f >> 3)) & 7);
}

// C[4096,512] = act(A[4096,K] @ W[512,K]^T + bias + noise_plane)
__global__ __launch_bounds__(256) void gemm_bias_noise(
    const float* __restrict__ A, const float* __restrict__ W,
    const float* __restrict__ bias, const float* __restrict__ noise,
    float* __restrict__ C, int K, int doTanh)
{
  const int N = HID;
  const int bm = blockIdx.y, bn = blockIdx.x;
  const int tid = threadIdx.x;
  const int tx = tid & 15, ty = tid >> 4;
  const int row0 = bm * 64, col0 = bn * 64;
  __shared__ float As[16][68];
  __shared__ float Ws[16][68];
  float acc[4][4] = {{0.f, 0.f, 0.f, 0.f}, {0.f, 0.f, 0.f, 0.f},
                     {0.f, 0.f, 0.f, 0.f}, {0.f, 0.f, 0.f, 0.f}};
  const int lrow = tid >> 2, lkq = tid & 3;
  for (int kt = 0; kt < K; kt += 16) {
    const float4 av = *(const float4*)&A[(size_t)(row0 + lrow) * K + kt + lkq * 4];
    const float4 wv = *(const float4*)&W[(size_t)(col0 + lrow) * K + kt + lkq * 4];
    __syncthreads();
    As[lkq * 4 + 0][lrow] = av.x; As[lkq * 4 + 1][lrow] = av.y;
    As[lkq * 4 + 2][lrow] = av.z; As[lkq * 4 + 3][lrow] = av.w;
    Ws[lkq * 4 + 0][lrow] = wv.x; Ws[lkq * 4 + 1][lrow] = wv.y;
    Ws[lkq * 4 + 2][lrow] = wv.z; Ws[lkq * 4 + 3][lrow] = wv.w;
    __syncthreads();
#pragma unroll
    for (int k = 0; k < 16; ++k) {
      const float4 a = *(const float4*)&As[k][ty * 4];
      const float4 bq = *(const float4*)&Ws[k][tx * 4];
      const float a4[4] = {a.x, a.y, a.z, a.w};
      const float b4[4] = {bq.x, bq.y, bq.z, bq.w};
#pragma unroll
      for (int i = 0; i < 4; ++i)
#pragma unroll
        for (int j = 0; j < 4; ++j)
          acc[i][j] = fmaf(a4[i], b4[j], acc[i][j]);
    }
  }
  const float4 bv = *(const float4*)&bias[col0 + tx * 4];
#pragma unroll
  for (int i = 0; i < 4; ++i) {
    const int row = row0 + ty * 4 + i;
    const float4 nv = *(const float4*)&noise[(size_t)row * N + col0 + tx * 4];
    float4 o;
    o.x = acc[i][0] + bv.x + nv.x;
    o.y = acc[i][1] + bv.y + nv.y;
    o.z = acc[i][2] + bv.z + nv.z;
    o.w = acc[i][3] + bv.w + nv.w;
    if (doTanh) {
      o.x = tanh_fast(o.x); o.y = tanh_fast(o.y);
      o.z = tanh_fast(o.z); o.w = tanh_fast(o.w);
    }
    *(float4*)&C[(size_t)row * N + col0 + tx * 4] = o;
  }
}

// Pre-fill the h-exchange buffer (= out plane 0) with the sentinel bits.
__global__ void fill_sentinel(uint4* __restrict__ p, int n4) {
  const int i = blockIdx.x * blockDim.x + threadIdx.x;
  if (i < n4) p[i] = make_uint4(SENT_BITS, SENT_BITS, SENT_BITS, SENT_BITS);
}

// Sequential scan h_t = tanh(drive_t + W_hh @ h_{t-1}).
// 8 blocks x 1024 thr (r2's proven sync population). Thread (i=tid>>4 row,
// j=tid&15 col-slice) holds W[base+i, 32j..32j+31] in 8 float4 regs.
// Per step:
//   - 448 pollers (tid<448) spin on ONE remote dword each, 2-deep pipelined
//     (check waits vmcnt(1); ~2x poll arrival rate), write into swizzled
//     double-buffered LDS (conflict-free scalar writes).
//   - ONE barrier.
//   - 8 swizzled ds_read_b128 (<=2-way) -> 32 FMA -> red16 (3 DPP + 1 swizzle).
//   - j==0: tanh, publish 1 agent dword (= out plane 0 / hs), seed own value
//     into the NEXT LDS buffer (own values never leave the CU; no 2nd barrier).
__global__ __launch_bounds__(1024) void recurrence(
    const float* __restrict__ Whh, const float* __restrict__ drive,
    const float* __restrict__ h0, unsigned* __restrict__ hexch)
{
  const int blk = blockIdx.x;
  const int base = blk * 64;
  const int tid = threadIdx.x;
  const int i = tid >> 4;        // local row 0..63
  const int j = tid & 15;        // col-slice 0..15
  const int row = base + i;

  __shared__ float hbuf[2][HID];

  // W slice -> 8 float4 regs (32 f32 — genuinely register-resident)
  float4 wv[8];
#pragma unroll
  for (int c = 0; c < 8; ++c)
    wv[c] = *(const float4*)&Whh[(size_t)row * HID + 32 * j + 4 * c];

  // poller mapping: remote float index g, swizzled LDS offset
  const int g = (tid < base) ? tid : tid + 64;               // valid for tid<448
  const int woff = swz(g >> 2) * 4 + (g & 3);
  // own-seed slot (j==0): float index row
  const int zown = swz(row >> 2) * 4 + (row & 3);

  // t=0 seed: all 512 floats from h0 (plain input)
  if (tid < HID) {
    hbuf[0][swz(tid >> 2) * 4 + (tid & 3)] = h0[tid];
  }

  for (int t = 0; t < SEQ; ++t) {
    const int buf = t & 1;

    float drv = 0.f;
    if (j == 0) drv = drive[(size_t)t * HID + row];   // issued before the spin

    if (t > 0 && tid < 448) {
      const unsigned* src = &hexch[(size_t)(t - 1) * HID + g];
      unsigned a = __hip_atomic_load(src, __ATOMIC_RELAXED,
                                     __HIP_MEMORY_SCOPE_AGENT);
      unsigned b = __hip_atomic_load(src, __ATOMIC_RELAXED,
                                     __HIP_MEMORY_SCOPE_AGENT);
      while (a == SENT_BITS) {
        a = b;
        b = __hip_atomic_load(src, __ATOMIC_RELAXED,
                              __HIP_MEMORY_SCOPE_AGENT);
      }
      hbuf[buf][woff] = __uint_as_float(a);
    }
    __syncthreads();   // buf ready; skew <= 1 step => other buffer safe
    asm volatile("" :: "v"(drv));   // keep drv load pre-poll, resident now

    float a0 = 0.f, a1 = 0.f, a2 = 0.f, a3 = 0.f;
#pragma unroll
    for (int c = 0; c < 8; ++c) {
      const float4 h4 = *(const float4*)&hbuf[buf][(8 * j + ((c ^ j) & 7)) * 4];
      a0 = fmaf(wv[c].x, h4.x, a0);
      a1 = fmaf(wv[c].y, h4.y, a1);
      a2 = fmaf(wv[c].z, h4.z, a2);
      a3 = fmaf(wv[c].w, h4.w, a3);
    }
    float sum = (a0 + a1) + (a2 + a3);
    sum = red16(sum);

    if (j == 0) {
      const float y = tanh_fast(sum + drv);
      // publish: agent store through the coherent point (proven r2 protocol)
      __hip_atomic_store(&hexch[(size_t)t * HID + row], __float_as_uint(y),
                         __ATOMIC_RELAXED, __HIP_MEMORY_SCOPE_AGENT);
      // own value never leaves the CU: seed next buffer directly.
      // Safe: all threads passed this step's barrier (done reading buf^1's
      // previous contents); t+1 pollers write disjoint slots.
      hbuf[buf ^ 1][zown] = y;
    }
  }
}

__global__ void copy_final(const float* __restrict__ src, float* __restrict__ dst) {
  dst[threadIdx.x] = src[threadIdx.x];
}

extern "C" void kernel_launch(void* const* d_in, const int* in_sizes, int n_in,
                              void* d_out, int out_size, void* d_ws, size_t ws_size,
                              hipStream_t stream) {
  const float* input    = (const float*)d_in[0];
  const float* internal = (const float*)d_in[1];
  const float* state    = (const float*)d_in[2];
  const float* W_ih     = (const float*)d_in[3];
  const float* W_hh     = (const float*)d_in[4];
  const float* bias     = (const float*)d_in[5];
  float* out = (float*)d_out;

  const size_t plane = (size_t)SEQ * HID;
  // hexch IS out plane 0 (hs): prefilled with sentinel, every element
  // overwritten exactly once by the recurrence.
  unsigned* hexch = (unsigned*)out;
  float*    drive = out + 5 * plane;   // rewritten by theta-GEMM k=4 afterwards

  fill_sentinel<<<(SEQ * HID / 4 + 255) / 256, 256, 0, stream>>>(
      (uint4*)hexch, SEQ * HID / 4);

  dim3 gg(HID / 64, SEQ / 64);
  // drive = x @ W_ih^T + b + internal[0]   (no tanh)
  gemm_bias_noise<<<gg, 256, 0, stream>>>(input, W_ih, bias, internal, drive,
                                          HID, 0);
  // hs (out plane 0, via sentinel exchange)
  recurrence<<<NBLK, 1024, 0, stream>>>(W_hh, drive, state, hexch);
  // theta rollouts: plane k -> plane k+1
  for (int k = 0; k < NTHETA; ++k) {
    gemm_bias_noise<<<gg, 256, 0, stream>>>(out + (size_t)k * plane, W_hh, bias,
                                            internal + (size_t)(k + 1) * plane,
                                            out + (size_t)(k + 1) * plane,
                                            HID, 1);
  }
  // final_state = hs[4095]
  copy_final<<<1, HID, 0, stream>>>(out + (size_t)4095 * HID, out + 6 * plane);
}

// Round 10
// 6744.753 us; speedup vs baseline: 4.1586x; 1.0055x over previous
//
#include <hip/hip_runtime.h>
#include <cstdint>
#include <cstddef>

#define SEQ 4096
#define HID 512
#define NTHETA 5
#define NBLK 8
#define SENT_BITS 0x40000000u   // 2.0f — |tanh| < 1, so never a real h value

__device__ __forceinline__ float tanh_fast(float x) {
  x = fminf(fmaxf(x, -20.0f), 20.0f);
  const float e = __expf(2.0f * x);
  return (e - 1.0f) / (e + 1.0f);
}

// 16B poll load, agent-visible (sc1 = device-scope flag on gfx950; same path
// __hip_atomic_load(AGENT) lowers to, but one request instead of four).
__device__ __forceinline__ uint4 load_x4_sc1(const unsigned* p) {
  uint4 u;
  asm volatile("global_load_dwordx4 %0, %1, off sc1\n\ts_waitcnt vmcnt(0)"
               : "=v"(u) : "v"(p) : "memory");
  return u;
}

// Butterfly sum over 16-lane groups: xor1, xor2, xor8 on the VALU (DPP
// quad_perm / row_ror:8), only xor4 on the DS pipe (ds_swizzle).
__device__ __forceinline__ float red16(float v) {
  int p;
  p = __builtin_amdgcn_update_dpp(0, __float_as_int(v), 0xB1, 0xF, 0xF, true);  // ^1
  v += __int_as_float(p);
  p = __builtin_amdgcn_update_dpp(0, __float_as_int(v), 0x4E, 0xF, 0xF, true);  // ^2
  v += __int_as_float(p);
  v += __int_as_float(__builtin_amdgcn_ds_swizzle(__float_as_int(v), 0x101F)); // ^4
  p = __builtin_amdgcn_update_dpp(0, __float_as_int(v), 0x128, 0xF, 0xF, true); // row_ror:8 = ^8
  v += __int_as_float(p);
  return v;
}

// f4-chunk swizzle: logical f4 chunk f -> LDS slot (<=2-way b128 reads,
// conflict-free b128 poll writes).
__device__ __forceinline__ int swz(int f) {
  return (f & ~7) | ((f ^ (f >> 3)) & 7);
}

// C[4096,512] = act(A[4096,K] @ W[512,K]^T + bias + noise_plane)
__global__ __launch_bounds__(256) void gemm_bias_noise(
    const float* __restrict__ A, const float* __restrict__ W,
    const float* __restrict__ bias, const float* __restrict__ noise,
    float* __restrict__ C, int K, int doTanh)
{
  const int N = HID;
  const int bm = blockIdx.y, bn = blockIdx.x;
  const int tid = threadIdx.x;
  const int tx = tid & 15, ty = tid >> 4;
  const int row0 = bm * 64, col0 = bn * 64;
  __shared__ float As[16][68];
  __shared__ float Ws[16][68];
  float acc[4][4] = {{0.f, 0.f, 0.f, 0.f}, {0.f, 0.f, 0.f, 0.f},
                     {0.f, 0.f, 0.f, 0.f}, {0.f, 0.f, 0.f, 0.f}};
  const int lrow = tid >> 2, lkq = tid & 3;
  for (int kt = 0; kt < K; kt += 16) {
    const float4 av = *(const float4*)&A[(size_t)(row0 + lrow) * K + kt + lkq * 4];
    const float4 wv = *(const float4*)&W[(size_t)(col0 + lrow) * K + kt + lkq * 4];
    __syncthreads();
    As[lkq * 4 + 0][lrow] = av.x; As[lkq * 4 + 1][lrow] = av.y;
    As[lkq * 4 + 2][lrow] = av.z; As[lkq * 4 + 3][lrow] = av.w;
    Ws[lkq * 4 + 0][lrow] = wv.x; Ws[lkq * 4 + 1][lrow] = wv.y;
    Ws[lkq * 4 + 2][lrow] = wv.z; Ws[lkq * 4 + 3][lrow] = wv.w;
    __syncthreads();
#pragma unroll
    for (int k = 0; k < 16; ++k) {
      const float4 a = *(const float4*)&As[k][ty * 4];
      const float4 bq = *(const float4*)&Ws[k][tx * 4];
      const float a4[4] = {a.x, a.y, a.z, a.w};
      const float b4[4] = {bq.x, bq.y, bq.z, bq.w};
#pragma unroll
      for (int i = 0; i < 4; ++i)
#pragma unroll
        for (int j = 0; j < 4; ++j)
          acc[i][j] = fmaf(a4[i], b4[j], acc[i][j]);
    }
  }
  const float4 bv = *(const float4*)&bias[col0 + tx * 4];
#pragma unroll
  for (int i = 0; i < 4; ++i) {
    const int row = row0 + ty * 4 + i;
    const float4 nv = *(const float4*)&noise[(size_t)row * N + col0 + tx * 4];
    float4 o;
    o.x = acc[i][0] + bv.x + nv.x;
    o.y = acc[i][1] + bv.y + nv.y;
    o.z = acc[i][2] + bv.z + nv.z;
    o.w = acc[i][3] + bv.w + nv.w;
    if (doTanh) {
      o.x = tanh_fast(o.x); o.y = tanh_fast(o.y);
      o.z = tanh_fast(o.z); o.w = tanh_fast(o.w);
    }
    *(float4*)&C[(size_t)row * N + col0 + tx * 4] = o;
  }
}

// Pre-fill the h-exchange buffer (= out plane 0) with the sentinel bits.
__global__ void fill_sentinel(uint4* __restrict__ p, int n4) {
  const int i = blockIdx.x * blockDim.x + threadIdx.x;
  if (i < n4) p[i] = make_uint4(SENT_BITS, SENT_BITS, SENT_BITS, SENT_BITS);
}

// Sequential scan h_t = tanh(drive_t + W_hh @ h_{t-1}).
// 8 blocks x 1024 thr. Thread (i=tid>>4 row, j=tid&15 col-slice) holds
// W[base+i, 32j..32j+31] in 8 float4 regs. Per step:
//   - 112 pollers (tid<112) spin on ONE 16B chunk each via
//     global_load_dwordx4 (4x fewer coherent-point requests than scalar;
//     producer stores are wave-coalesced at the same 16B granularity, so
//     chunks arrive atomically in practice; every value transitions once).
//     Every 8th spin falls back to 4 scalar agent-atomic loads (proven r2
//     primitive) so a wrong cache flag degrades, never hangs.
//   - detected chunk -> one ds_write_b128 into the swizzled double buffer.
//   - ONE barrier.
//   - 8 swizzled ds_read_b128 (<=2-way) -> 32 FMA -> red16 (3 DPP + 1 swizzle).
//   - j==0: tanh, publish 1 agent dword (= out plane 0 / hs), seed own value
//     into the NEXT LDS buffer (own values never leave the CU; no 2nd barrier).
__global__ __launch_bounds__(1024) void recurrence(
    const float* __restrict__ Whh, const float* __restrict__ drive,
    const float* __restrict__ h0, unsigned* __restrict__ hexch)
{
  const int blk = blockIdx.x;
  const int base = blk * 64;
  const int tid = threadIdx.x;
  const int i = tid >> 4;        // local row 0..63
  const int j = tid & 15;        // col-slice 0..15
  const int row = base + i;

  __shared__ __align__(16) float hbuf[2][HID];

  // W slice -> 8 float4 regs (32 f32, register-resident)
  float4 wv[8];
#pragma unroll
  for (int c = 0; c < 8; ++c)
    wv[c] = *(const float4*)&Whh[(size_t)row * HID + 32 * j + 4 * c];

  // poller mapping: remote f4-chunk index (skip own 16 chunks), swizzled slot
  const int ch = (tid < blk * 16) ? tid : tid + 16;          // valid for tid<112
  const int wslot = swz(ch);
  // own-seed slot (j==0): float index row
  const int zown = swz(row >> 2) * 4 + (row & 3);

  // t=0 seed: all 512 floats from h0 (plain input)
  if (tid < HID) {
    hbuf[0][swz(tid >> 2) * 4 + (tid & 3)] = h0[tid];
  }

  for (int t = 0; t < SEQ; ++t) {
    const int buf = t & 1;

    float drv = 0.f;
    if (j == 0) drv = drive[(size_t)t * HID + row];   // issued before the spin

    if (t > 0 && tid < 112) {
      const unsigned* src = &hexch[(size_t)(t - 1) * HID + 4 * ch];
      uint4 u = load_x4_sc1(src);
      int it = 0;
      while (u.x == SENT_BITS || u.y == SENT_BITS ||
             u.z == SENT_BITS || u.w == SENT_BITS) {
        if ((++it & 7) == 0) {
          u.x = __hip_atomic_load(src + 0, __ATOMIC_RELAXED,
                                  __HIP_MEMORY_SCOPE_AGENT);
          u.y = __hip_atomic_load(src + 1, __ATOMIC_RELAXED,
                                  __HIP_MEMORY_SCOPE_AGENT);
          u.z = __hip_atomic_load(src + 2, __ATOMIC_RELAXED,
                                  __HIP_MEMORY_SCOPE_AGENT);
          u.w = __hip_atomic_load(src + 3, __ATOMIC_RELAXED,
                                  __HIP_MEMORY_SCOPE_AGENT);
        } else {
          u = load_x4_sc1(src);
        }
      }
      ((uint4*)hbuf[buf])[wslot] = u;   // one ds_write_b128, swizzled slot
    }
    __syncthreads();   // buf ready; skew <= 1 step => other buffer safe
    asm volatile("" :: "v"(drv));   // keep drv load pre-poll, resident now

    float a0 = 0.f, a1 = 0.f, a2 = 0.f, a3 = 0.f;
#pragma unroll
    for (int c = 0; c < 8; ++c) {
      const float4 h4 = *(const float4*)&hbuf[buf][(8 * j + ((c ^ j) & 7)) * 4];
      a0 = fmaf(wv[c].x, h4.x, a0);
      a1 = fmaf(wv[c].y, h4.y, a1);
      a2 = fmaf(wv[c].z, h4.z, a2);
      a3 = fmaf(wv[c].w, h4.w, a3);
    }
    float sum = (a0 + a1) + (a2 + a3);
    sum = red16(sum);

    if (j == 0) {
      const float y = tanh_fast(sum + drv);
      // publish: agent store through the coherent point (proven r2 protocol);
      // lanes 0/16/32/48 of each wave coalesce into one 16B transaction,
      // matching the consumer's 16B poll granularity.
      __hip_atomic_store(&hexch[(size_t)t * HID + row], __float_as_uint(y),
                         __ATOMIC_RELAXED, __HIP_MEMORY_SCOPE_AGENT);
      // own value never leaves the CU: seed next buffer directly.
      hbuf[buf ^ 1][zown] = y;
    }
  }
}

__global__ void copy_final(const float* __restrict__ src, float* __restrict__ dst) {
  dst[threadIdx.x] = src[threadIdx.x];
}

extern "C" void kernel_launch(void* const* d_in, const int* in_sizes, int n_in,
                              void* d_out, int out_size, void* d_ws, size_t ws_size,
                              hipStream_t stream) {
  const float* input    = (const float*)d_in[0];
  const float* internal = (const float*)d_in[1];
  const float* state    = (const float*)d_in[2];
  const float* W_ih     = (const float*)d_in[3];
  const float* W_hh     = (const float*)d_in[4];
  const float* bias     = (const float*)d_in[5];
  float* out = (float*)d_out;

  const size_t plane = (size_t)SEQ * HID;
  // hexch IS out plane 0 (hs): prefilled with sentinel, every element
  // overwritten exactly once by the recurrence.
  unsigned* hexch = (unsigned*)out;
  float*    drive = out + 5 * plane;   // rewritten by theta-GEMM k=4 afterwards

  fill_sentinel<<<(SEQ * HID / 4 + 255) / 256, 256, 0, stream>>>(
      (uint4*)hexch, SEQ * HID / 4);

  dim3 gg(HID / 64, SEQ / 64);
  // drive = x @ W_ih^T + b + internal[0]   (no tanh)
  gemm_bias_noise<<<gg, 256, 0, stream>>>(input, W_ih, bias, internal, drive,
                                          HID, 0);
  // hs (out plane 0, via sentinel exchange)
  recurrence<<<NBLK, 1024, 0, stream>>>(W_hh, drive, state, hexch);
  // theta rollouts: plane k -> plane k+1
  for (int k = 0; k < NTHETA; ++k) {
    gemm_bias_noise<<<gg, 256, 0, stream>>>(out + (size_t)k * plane, W_hh, bias,
                                            internal + (size_t)(k + 1) * plane,
                                            out + (size_t)(k + 1) * plane,
                                            HID, 1);
  }
  // final_state = hs[4095]
  copy_final<<<1, HID, 0, stream>>>(out + (size_t)4095 * HID, out + 6 * plane);
}

// Round 13
// 6501.093 us; speedup vs baseline: 4.3145x; 1.0375x over previous
//
#include <hip/hip_runtime.h>
#include <cstdint>
#include <cstddef>

#define SEQ 4096
#define HID 512
#define NTHETA 5
#define NBLK 4
#define RPB 128                 // rows per block
#define SENT_BITS 0x40000000u   // 2.0f — |tanh| < 1, so never a real h value

typedef unsigned long long u64;

__device__ __forceinline__ float tanh_fast(float x) {
  x = fminf(fmaxf(x, -20.0f), 20.0f);
  const float e = __expf(2.0f * x);
  return (e - 1.0f) / (e + 1.0f);
}

// 16B poll load, agent-visible (sc1 path verified working at full speed, r10).
// Wait is INSIDE the asm: nothing stays in flight across loop exits, so no
// register-liveness hazard (r12's corruption mechanism is structurally absent).
__device__ __forceinline__ uint4 load_x4_sc1(const unsigned* p) {
  uint4 u;
  asm volatile("global_load_dwordx4 %0, %1, off sc1\n\ts_waitcnt vmcnt(0)"
               : "=v"(u) : "v"(p) : "memory");
  return u;
}

// Butterfly sum over 16-lane groups: xor1, xor2, xor8 on the VALU (DPP),
// only xor4 on the DS pipe (ds_swizzle). Verified r9/r10.
__device__ __forceinline__ float red16(float v) {
  int p;
  p = __builtin_amdgcn_update_dpp(0, __float_as_int(v), 0xB1, 0xF, 0xF, true);  // ^1
  v += __int_as_float(p);
  p = __builtin_amdgcn_update_dpp(0, __float_as_int(v), 0x4E, 0xF, 0xF, true);  // ^2
  v += __int_as_float(p);
  v += __int_as_float(__builtin_amdgcn_ds_swizzle(__float_as_int(v), 0x101F)); // ^4
  p = __builtin_amdgcn_update_dpp(0, __float_as_int(v), 0x128, 0xF, 0xF, true); // row_ror:8 = ^8
  v += __int_as_float(p);
  return v;
}

// f4-chunk swizzle (<=2-way b128 reads, conflict-free b128 poll writes)
__device__ __forceinline__ int swz(int f) {
  return (f & ~7) | ((f ^ (f >> 3)) & 7);
}

// C[4096,512] = act(A[4096,K] @ W[512,K]^T + bias + noise_plane)
__global__ __launch_bounds__(256) void gemm_bias_noise(
    const float* __restrict__ A, const float* __restrict__ W,
    const float* __restrict__ bias, const float* __restrict__ noise,
    float* __restrict__ C, int K, int doTanh)
{
  const int N = HID;
  const int bm = blockIdx.y, bn = blockIdx.x;
  const int tid = threadIdx.x;
  const int tx = tid & 15, ty = tid >> 4;
  const int row0 = bm * 64, col0 = bn * 64;
  __shared__ float As[16][68];
  __shared__ float Ws[16][68];
  float acc[4][4] = {{0.f, 0.f, 0.f, 0.f}, {0.f, 0.f, 0.f, 0.f},
                     {0.f, 0.f, 0.f, 0.f}, {0.f, 0.f, 0.f, 0.f}};
  const int lrow = tid >> 2, lkq = tid & 3;
  for (int kt = 0; kt < K; kt += 16) {
    const float4 av = *(const float4*)&A[(size_t)(row0 + lrow) * K + kt + lkq * 4];
    const float4 wv = *(const float4*)&W[(size_t)(col0 + lrow) * K + kt + lkq * 4];
    __syncthreads();
    As[lkq * 4 + 0][lrow] = av.x; As[lkq * 4 + 1][lrow] = av.y;
    As[lkq * 4 + 2][lrow] = av.z; As[lkq * 4 + 3][lrow] = av.w;
    Ws[lkq * 4 + 0][lrow] = wv.x; Ws[lkq * 4 + 1][lrow] = wv.y;
    Ws[lkq * 4 + 2][lrow] = wv.z; Ws[lkq * 4 + 3][lrow] = wv.w;
    __syncthreads();
#pragma unroll
    for (int k = 0; k < 16; ++k) {
      const float4 a = *(const float4*)&As[k][ty * 4];
      const float4 bq = *(const float4*)&Ws[k][tx * 4];
      const float a4[4] = {a.x, a.y, a.z, a.w};
      const float b4[4] = {bq.x, bq.y, bq.z, bq.w};
#pragma unroll
      for (int i = 0; i < 4; ++i)
#pragma unroll
        for (int j = 0; j < 4; ++j)
          acc[i][j] = fmaf(a4[i], b4[j], acc[i][j]);
    }
  }
  const float4 bv = *(const float4*)&bias[col0 + tx * 4];
#pragma unroll
  for (int i = 0; i < 4; ++i) {
    const int row = row0 + ty * 4 + i;
    const float4 nv = *(const float4*)&noise[(size_t)row * N + col0 + tx * 4];
    float4 o;
    o.x = acc[i][0] + bv.x + nv.x;
    o.y = acc[i][1] + bv.y + nv.y;
    o.z = acc[i][2] + bv.z + nv.z;
    o.w = acc[i][3] + bv.w + nv.w;
    if (doTanh) {
      o.x = tanh_fast(o.x); o.y = tanh_fast(o.y);
      o.z = tanh_fast(o.z); o.w = tanh_fast(o.w);
    }
    *(float4*)&C[(size_t)row * N + col0 + tx * 4] = o;
  }
}

// Pre-fill the h-exchange buffer (= out plane 0) with the sentinel bits.
__global__ void fill_sentinel(uint4* __restrict__ p, int n4) {
  const int i = blockIdx.x * blockDim.x + threadIdx.x;
  if (i < n4) p[i] = make_uint4(SENT_BITS, SENT_BITS, SENT_BITS, SENT_BITS);
}

// Sequential scan h_t = tanh(drive_t + W_hh @ h_{t-1}).
// 4 blocks x 1024 thr; block owns 128 rows. Thread (i=tid>>4, j=tid&15)
// owns rows r0=base+2i, r0+1, cols 32j..+31 (16 float4 W regs). Per step:
//   - 96 pollers (tid<96) spin on one remote 16B chunk each via the r10
//     sequential sc1-x4 poll (wait-in-asm; every 8th: scalar agent backstop).
//   - detected chunk -> one ds_write_b128 (swizzled slot); ONE barrier.
//   - 8 swizzled ds_read_b128 (<=2-way) -> 64 FMA (2 rows, h4 reused)
//     -> 2x red16 (3 DPP + 1 ds_swizzle).
//   - j==0: 2x tanh, ONE u64 agent publish (rows r0,r0+1; r8-proven
//     primitive), seed own float2 into next LDS buffer (no 2nd barrier).
// Lever under test vs r10: NBLK 8 -> 4 (producer-straggler max + fewer
// remote deps). Everything else is correctness-proven machinery.
__global__ __launch_bounds__(1024) void recurrence(
    const float* __restrict__ Whh, const float* __restrict__ drive,
    const float* __restrict__ h0, unsigned* __restrict__ hexch)
{
  const int blk = blockIdx.x;
  const int base = blk * RPB;
  const int tid = threadIdx.x;
  const int i = tid >> 4;        // 0..63
  const int j = tid & 15;        // 0..15
  const int r0 = base + 2 * i;   // first of this thread's two rows

  __shared__ __align__(16) float hbuf[2][HID];

  // W: 2 rows x 32 cols -> 16 float4 regs
  float4 w0[8], w1[8];
#pragma unroll
  for (int c = 0; c < 8; ++c) {
    w0[c] = *(const float4*)&Whh[(size_t)r0 * HID + 32 * j + 4 * c];
    w1[c] = *(const float4*)&Whh[(size_t)(r0 + 1) * HID + 32 * j + 4 * c];
  }

  // poller mapping: tid<96 -> remote f4 chunk (skip own 32), swizzled slot
  const int ch = (tid < blk * 32) ? tid : tid + 32;   // valid for tid<96
  const int wslot = swz(ch);
  // own-seed slot (j==0): rows r0,r0+1 -> chunk r0>>2, offset r0&3 (0 or 2)
  const int z0 = swz(r0 >> 2) * 4 + (r0 & 3);

  // t=0 seed from h0
  if (tid < HID) hbuf[0][swz(tid >> 2) * 4 + (tid & 3)] = h0[tid];

  for (int t = 0; t < SEQ; ++t) {
    const int buf = t & 1;

    float2 dr = make_float2(0.f, 0.f);
    if (j == 0) dr = *(const float2*)&drive[(size_t)t * HID + r0];

    if (t > 0 && tid < 96) {
      const unsigned* src = &hexch[(size_t)(t - 1) * HID + 4 * ch];
      uint4 u = load_x4_sc1(src);
      int it = 0;
      while (u.x == SENT_BITS || u.y == SENT_BITS ||
             u.z == SENT_BITS || u.w == SENT_BITS) {
        if ((++it & 7) == 0) {
          u.x = __hip_atomic_load(src + 0, __ATOMIC_RELAXED,
                                  __HIP_MEMORY_SCOPE_AGENT);
          u.y = __hip_atomic_load(src + 1, __ATOMIC_RELAXED,
                                  __HIP_MEMORY_SCOPE_AGENT);
          u.z = __hip_atomic_load(src + 2, __ATOMIC_RELAXED,
                                  __HIP_MEMORY_SCOPE_AGENT);
          u.w = __hip_atomic_load(src + 3, __ATOMIC_RELAXED,
                                  __HIP_MEMORY_SCOPE_AGENT);
        } else {
          u = load_x4_sc1(src);
        }
      }
      ((uint4*)hbuf[buf])[wslot] = u;   // one ds_write_b128, swizzled slot
    }
    __syncthreads();   // buf ready; skew <= 1 step => other buffer safe
    asm volatile("" :: "v"(dr.x), "v"(dr.y));   // drv resident by now

    float a00 = 0.f, a01 = 0.f, a02 = 0.f, a03 = 0.f;
    float a10 = 0.f, a11 = 0.f, a12 = 0.f, a13 = 0.f;
#pragma unroll
    for (int c = 0; c < 8; ++c) {
      const float4 h4 = *(const float4*)&hbuf[buf][(8 * j + ((c ^ j) & 7)) * 4];
      a00 = fmaf(w0[c].x, h4.x, a00);
      a01 = fmaf(w0[c].y, h4.y, a01);
      a02 = fmaf(w0[c].z, h4.z, a02);
      a03 = fmaf(w0[c].w, h4.w, a03);
      a10 = fmaf(w1[c].x, h4.x, a10);
      a11 = fmaf(w1[c].y, h4.y, a11);
      a12 = fmaf(w1[c].z, h4.z, a12);
      a13 = fmaf(w1[c].w, h4.w, a13);
    }
    float s0 = red16((a00 + a01) + (a02 + a03));
    float s1 = red16((a10 + a11) + (a12 + a13));

    if (j == 0) {
      const float y0 = tanh_fast(s0 + dr.x);
      const float y1 = tanh_fast(s1 + dr.y);
      const u64 pk = (u64)__float_as_uint(y0) | ((u64)__float_as_uint(y1) << 32);
      // ONE u64 agent publish (r8-proven primitive); lanes 0/16/32/48 of a
      // wave coalesce into one contiguous 32B transaction.
      __hip_atomic_store((u64*)&hexch[(size_t)t * HID + r0], pk,
                         __ATOMIC_RELAXED, __HIP_MEMORY_SCOPE_AGENT);
      // own rows never leave the CU: seed next LDS buffer directly.
      *(float2*)&hbuf[buf ^ 1][z0] = make_float2(y0, y1);
    }
  }
}

__global__ void copy_final(const float* __restrict__ src, float* __restrict__ dst) {
  dst[threadIdx.x] = src[threadIdx.x];
}

extern "C" void kernel_launch(void* const* d_in, const int* in_sizes, int n_in,
                              void* d_out, int out_size, void* d_ws, size_t ws_size,
                              hipStream_t stream) {
  const float* input    = (const float*)d_in[0];
  const float* internal = (const float*)d_in[1];
  const float* state    = (const float*)d_in[2];
  const float* W_ih     = (const float*)d_in[3];
  const float* W_hh     = (const float*)d_in[4];
  const float* bias     = (const float*)d_in[5];
  float* out = (float*)d_out;

  const size_t plane = (size_t)SEQ * HID;
  // hexch IS out plane 0 (hs): prefilled with sentinel, every element
  // overwritten exactly once by the recurrence.
  unsigned* hexch = (unsigned*)out;
  float*    drive = out + 5 * plane;   // rewritten by theta-GEMM k=4 afterwards

  fill_sentinel<<<(SEQ * HID / 4 + 255) / 256, 256, 0, stream>>>(
      (uint4*)hexch, SEQ * HID / 4);

  dim3 gg(HID / 64, SEQ / 64);
  // drive = x @ W_ih^T + b + internal[0]   (no tanh)
  gemm_bias_noise<<<gg, 256, 0, stream>>>(input, W_ih, bias, internal, drive,
                                          HID, 0);
  // hs (out plane 0, via sentinel exchange)
  recurrence<<<NBLK, 1024, 0, stream>>>(W_hh, drive, state, hexch);
  // theta rollouts: plane k -> plane k+1
  for (int k = 0; k < NTHETA; ++k) {
    gemm_bias_noise<<<gg, 256, 0, stream>>>(out + (size_t)k * plane, W_hh, bias,
                                            internal + (size_t)(k + 1) * plane,
                                            out + (size_t)(k + 1) * plane,
                                            HID, 1);
  }
  // final_state = hs[4095]
  copy_final<<<1, HID, 0, stream>>>(out + (size_t)4095 * HID, out + 6 * plane);
}